// Round 1
// baseline (281.216 us; speedup 1.0000x reference)
//
#include <hip/hip_runtime.h>

// Morphological opening (22x22 flat SE) = erode(min) then dilate(max),
// each separable into row + col 1D sliding-window passes, window [i-11, i+10].
//
// Pass plan (ws = d_ws, needs 24*1024*1024*4 = 100.7 MB):
//   pass_row<min>: in  -> ws
//   pass_col<min>: ws  -> out      (out = eroded)
//   pass_row<max>: out -> ws
//   pass_col<max>: ws  -> out      (out = opened)
//
// 1D windows computed with van Herk / Gil-Werman (block size 22 prefix/suffix
// mins): ~3-4 ops + ~1.3 loads per output instead of 22 taps.

#define HH 1024
#define WW 1024
#define PLANES 24          // 8 * 3
#define KW 22
#define HALO_L 11          // window for output i: [i-11, i+10]

template<bool IS_MIN>
__device__ __forceinline__ float vop(float a, float b) {
    return IS_MIN ? fminf(a, b) : fmaxf(a, b);
}

// van Herk 1D: outputs k in [0,C). get(p) returns input at position s+p where
// s = a - 11 (a = first output index); put(k,val) consumes output k.
// NB = ceil((C+21)/22) blocks of 22.
template<bool IS_MIN, int C, int NB, class Get, class Put>
__device__ __forceinline__ void vanherk(Get get, Put put) {
    const float ID = IS_MIN ? __builtin_inff() : -__builtin_inff();
    float Sprev[KW];   // suffix mins of previous block
    #pragma unroll
    for (int j = 0; j < NB; ++j) {
        const int base = KW * j;
        // max element index needed in this block (for last, partial block)
        const int needed = (C + KW - 1 - base) < KW ? (C + KW - 1 - base) : KW;
        float v[KW];
        #pragma unroll
        for (int m = 0; m < KW; ++m)
            v[m] = (m < needed) ? get(base + m) : ID;
        // running prefix + emit
        float p = ID;
        #pragma unroll
        for (int m = 0; m < KW; ++m) {
            if (m < needed) {
                p = vop<IS_MIN>(p, v[m]);
                const int k = base - (KW - 1) + m;   // output whose r lands here
                if (m == KW - 1) {
                    if (k >= 0 && k < C) put(k, p);  // window == whole block
                } else if (k >= 0 && k < C) {
                    put(k, vop<IS_MIN>(Sprev[m + 1], p));
                }
            }
        }
        // suffix mins for next block's emits
        if (j < NB - 1) {
            float sfx = ID;
            #pragma unroll
            for (int m = KW - 1; m >= 0; --m) {
                sfx = vop<IS_MIN>(sfx, v[m]);
                Sprev[m] = sfx;
            }
        }
    }
}

// ---------------- Row pass ----------------
// Block: 256 threads, 4 image rows, full 1024-wide. Each thread: 16 outputs.
// LDS swizzle: col -> 33*(col>>5) + (col&31), row stride 1056 ==> every access
// pattern here is <=2-way bank aliased (free on CDNA4).
__device__ __forceinline__ int sw_idx(int r, int c) {
    return r * 1056 + 33 * (c >> 5) + (c & 31);
}

template<bool IS_MIN>
__global__ __launch_bounds__(256) void pass_row(const float* __restrict__ in,
                                                float* __restrict__ out) {
    const int ROWS = 4;
    const int CH = 16;                      // output cols per thread
    __shared__ float lds[ROWS * 1056];

    const int plane = blockIdx.x >> 8;      // 256 row-groups per plane
    const int row0 = (blockIdx.x & 255) * ROWS;
    const size_t planeOff = (size_t)plane * ((size_t)HH * WW);
    const float* src = in + planeOff + (size_t)row0 * WW;
    float* dst = out + planeOff + (size_t)row0 * WW;
    const int t = threadIdx.x;
    const float ID = IS_MIN ? __builtin_inff() : -__builtin_inff();

    // stage 4 rows (4096 floats) coalesced, float4
    const float4* src4 = (const float4*)src;
    #pragma unroll
    for (int kk = 0; kk < 4; ++kk) {
        int vi = t + 256 * kk;              // float4 index; row kk, col 4*t
        float4 x = src4[vi];
        int e = vi << 2;
        int r = e >> 10;
        int c = e & 1023;
        int b = sw_idx(r, c);
        lds[b + 0] = x.x; lds[b + 1] = x.y; lds[b + 2] = x.z; lds[b + 3] = x.w;
    }
    __syncthreads();

    // van Herk per thread from LDS into registers
    const int r = t >> 6;                   // 4 rows
    const int chunk = t & 63;               // 64 chunks of 16 cols
    const int a = chunk * CH;
    const int s = a - HALO_L;
    float res[CH];
    vanherk<IS_MIN, CH, 2>(
        [&](int p) {
            int col = s + p;
            float v = ID;
            if (col >= 0 && col < WW) v = lds[sw_idx(r, col)];
            return v;
        },
        [&](int k, float val) { res[k] = val; });
    __syncthreads();

    // write results back to LDS (overwrite), then coalesced float4 store
    #pragma unroll
    for (int k = 0; k < CH; ++k)
        lds[sw_idx(r, a + k)] = res[k];
    __syncthreads();

    float4* dst4 = (float4*)dst;
    #pragma unroll
    for (int kk = 0; kk < 4; ++kk) {
        int vi = t + 256 * kk;
        int e = vi << 2;
        int rr = e >> 10;
        int c = e & 1023;
        int b = sw_idx(rr, c);
        float4 x;
        x.x = lds[b + 0]; x.y = lds[b + 1]; x.z = lds[b + 2]; x.w = lds[b + 3];
        dst4[vi] = x;
    }
}

// ---------------- Col pass ----------------
// Thread <-> (plane, 64-row chunk, column). Loads/stores coalesced across
// consecutive columns; van Herk fully in registers, no LDS.
template<bool IS_MIN>
__global__ __launch_bounds__(256) void pass_col(const float* __restrict__ in,
                                                float* __restrict__ out) {
    const int CR = 64;                      // output rows per thread
    int tid = blockIdx.x * 256 + threadIdx.x;
    int col = tid & (WW - 1);
    int rest = tid >> 10;
    int chunk = rest & 15;                  // 1024/64 = 16 chunks
    int plane = rest >> 4;
    const size_t planeOff = (size_t)plane * ((size_t)HH * WW);
    const float* src = in + planeOff + col;
    float* dst = out + planeOff + col;
    const int a = chunk * CR;
    const int s = a - HALO_L;
    const float ID = IS_MIN ? __builtin_inff() : -__builtin_inff();

    vanherk<IS_MIN, CR, 4>(
        [&](int p) {
            int row = s + p;
            float v = ID;
            if (row >= 0 && row < HH) v = src[(size_t)row * WW];
            return v;
        },
        [&](int k, float val) { dst[(size_t)(a + k) * WW] = val; });
}

extern "C" void kernel_launch(void* const* d_in, const int* in_sizes, int n_in,
                              void* d_out, int out_size, void* d_ws, size_t ws_size,
                              hipStream_t stream) {
    const float* in = (const float*)d_in[0];
    float* out = (float*)d_out;
    float* ws = (float*)d_ws;   // needs 24*1024*1024*4 B = 100.7 MB

    const int rowGrid = PLANES * (HH / 4);      // 6144 blocks
    const int colGrid = PLANES * 16 * WW / 256; // 1536 blocks

    pass_row<true ><<<rowGrid, 256, 0, stream>>>(in, ws);   // erode rows
    pass_col<true ><<<colGrid, 256, 0, stream>>>(ws, out);  // erode cols
    pass_row<false><<<rowGrid, 256, 0, stream>>>(out, ws);  // dilate rows
    pass_col<false><<<colGrid, 256, 0, stream>>>(ws, out);  // dilate cols
}

// Round 2
// 250.699 us; speedup vs baseline: 1.1217x; 1.1217x over previous
//
#include <hip/hip_runtime.h>

// Fully-fused morphological opening (22x22 flat SE) on 8x3x1024x1024 f32.
// opening = dilate(erode(x)); both separable => 4 1D sliding-window passes
// (rowmin, colmin, rowmax, colmax), all fused into ONE kernel per 64x64
// output tile, staged through a single in-place-reused LDS buffer.
//
// Window for output i: [i-11, i+10] (kornia origin = k//2 = 11).
// Erosion pads +inf; dilation pads -inf OUTSIDE THE IMAGE (eroded values at
// out-of-image positions are -inf, not erosion of padded input).
//
// Per block (output tile rows [R,R+64), cols [C,C+64)):
//   S0: load input rows [R-22,R+84) x cols [C-24,C+84) -> LDS A (106x108,
//       stride 109, odd => column accesses conflict-free), +inf out of image.
//   S1: rowmin  -> A[row][0..85)   (van Herk, regs -> barrier -> in-place)
//   S2: colmin  -> eroded 85x85, -inf override outside image
//   S3: rowmax  -> 85x64
//   S4: colmax  -> 64x64, direct coalesced global store.

#define HH 1024
#define WW 1024
#define KW 22
#define SA 109            // LDS row stride (odd -> conflict-free col reads)
#define PINF __builtin_inff()

template<bool IS_MIN>
__device__ __forceinline__ float vop(float a, float b) {
    return IS_MIN ? fminf(a, b) : fmaxf(a, b);
}

// van Herk / Gil-Werman 1D sliding window, runtime output count cout<=CMAX.
// get(p): input at window-space position p (output k's window = get(k..k+21)).
// put(k,v): consume output k, k in [0,cout).
template<bool IS_MIN, int CMAX, class Get, class Put>
__device__ __forceinline__ void vanherk(int cout, Get get, Put put) {
    const float ID = IS_MIN ? PINF : -PINF;
    constexpr int NB = (CMAX + 2 * KW - 2) / KW;   // ceil((CMAX+21)/22)
    float Sprev[KW];
    #pragma unroll
    for (int j = 0; j < NB; ++j) {
        const int base = KW * j;
        int needed = cout + KW - 1 - base;          // #inputs in this block
        if (needed > KW) needed = KW;               // may be <= 0
        float v[KW];
        #pragma unroll
        for (int m = 0; m < KW; ++m)
            v[m] = (m < needed) ? get(base + m) : ID;
        float p = ID;
        #pragma unroll
        for (int m = 0; m < KW; ++m) {
            p = vop<IS_MIN>(p, v[m]);
            const int k = base - (KW - 1) + m;      // output ending here
            if (k >= 0) {
                if (m == KW - 1) {
                    if (k < cout) put(k, p);
                } else {
                    if (k < cout) put(k, vop<IS_MIN>(Sprev[m + 1], p));
                }
            }
        }
        if (j < NB - 1) {
            float s = ID;
            #pragma unroll
            for (int m = KW - 1; m >= 0; --m) {
                s = vop<IS_MIN>(s, v[m]);
                Sprev[m] = s;
            }
        }
    }
}

__global__ __launch_bounds__(256) void fused_open(const float* __restrict__ in,
                                                  float* __restrict__ out) {
    __shared__ float A[106 * SA];
    const int t = threadIdx.x;
    const int b = blockIdx.x;
    const int plane = b >> 8;
    const int by = (b >> 4) & 15;
    const int bx = b & 15;
    const int R = by * 64, C = bx * 64;
    const float* src = in + (size_t)plane * (HH * WW);
    float* dst = out + (size_t)plane * (HH * WW);

    // ---- S0: stage input halo tile (106 rows x 27 float4) ----
    for (int i = t; i < 106 * 27; i += 256) {
        int row = i / 27;
        int c4 = i - row * 27;
        int ir = R - 22 + row;
        int ic = C - 24 + 4 * c4;              // multiple of 4; f4 all-in or all-out
        float4 x = make_float4(PINF, PINF, PINF, PINF);
        if ((unsigned)ir < HH && (unsigned)ic < WW)
            x = *(const float4*)(src + (size_t)ir * WW + ic);
        int a = row * SA + 4 * c4;
        A[a] = x.x; A[a + 1] = x.y; A[a + 2] = x.z; A[a + 3] = x.w;
    }
    __syncthreads();

    float res[43];
    int row = 0, ch = 0, cout = 0;

    // ---- S1: rowmin. 212 tasks = 106 rows x 2 chunks (43,42). ----
    // rowmin(row, e) (e = eroded-col index, img col C-11+e) needs buffer
    // cols [e+2, e+23]; get-space origin = bc 2.
    bool act = t < 212;
    if (act) {
        row = t >> 1; ch = t & 1;
        cout = ch ? 42 : 43;
        const int e0 = ch * 43;
        const float* Ar = &A[row * SA];
        vanherk<true, 43>(cout,
            [&](int p) { return Ar[e0 + 2 + p]; },
            [&](int k, float v) { res[k] = v; });
    }
    __syncthreads();
    if (act) {
        float* Ar = &A[row * SA];
        const int e0 = (t & 1) * 43;
        #pragma unroll
        for (int k = 0; k < 43; ++k)
            if (k < cout) Ar[e0 + k] = res[k];
    }
    __syncthreads();

    // ---- S2: colmin -> eroded(r^,e), r^ in [0,85) (img row R-11+r^). ----
    // 170 tasks = 85 cols x 2 chunks (43,42). Border override to -inf.
    act = t < 170;
    int e = 0, r0 = 0;
    if (act) {
        e = t >> 1; ch = t & 1;
        r0 = ch * 43;
        cout = ch ? 42 : 43;
        vanherk<true, 43>(cout,
            [&](int p) { return A[(r0 + p) * SA + e]; },
            [&](int k, float v) { res[k] = v; });
        const int img_c = C - 11 + e;
        const bool c_ok = (unsigned)img_c < WW;
        #pragma unroll
        for (int k = 0; k < 43; ++k) {
            int img_r = R - 11 + r0 + k;
            if (!c_ok || (unsigned)img_r >= HH) res[k] = -PINF;
        }
    }
    __syncthreads();
    if (act) {
        #pragma unroll
        for (int k = 0; k < 43; ++k)
            if (k < cout) A[(r0 + k) * SA + e] = res[k];
    }
    __syncthreads();

    // ---- S3: rowmax(r^, c), c in [0,64): needs eroded cols [c, c+21]. ----
    // 170 tasks = 85 rows x 2 chunks of 32.
    act = t < 170;
    if (act) {
        row = t >> 1; ch = t & 1;
        const int c0 = ch * 32;
        const float* Ar = &A[row * SA];
        vanherk<false, 32>(32,
            [&](int p) { return Ar[c0 + p]; },
            [&](int k, float v) { res[k] = v; });
    }
    __syncthreads();
    if (act) {
        float* Ar = &A[row * SA];
        const int c0 = (t & 1) * 32;
        #pragma unroll
        for (int k = 0; k < 32; ++k)
            Ar[c0 + k] = res[k];
    }
    __syncthreads();

    // ---- S4: colmax -> out. 256 tasks = 64 cols x 4 chunks of 16 rows. ----
    // out(y,c) needs rowmax rows [y, y+21]. Lanes = consecutive cols =>
    // coalesced 256B global stores.
    {
        const int c = t & 63;
        const int y0 = (t >> 6) * 16;
        float o[16];
        vanherk<false, 16>(16,
            [&](int p) { return A[(y0 + p) * SA + c]; },
            [&](int k, float v) { o[k] = v; });
        #pragma unroll
        for (int k = 0; k < 16; ++k)
            dst[(size_t)(R + y0 + k) * WW + C + c] = o[k];
    }
}

extern "C" void kernel_launch(void* const* d_in, const int* in_sizes, int n_in,
                              void* d_out, int out_size, void* d_ws, size_t ws_size,
                              hipStream_t stream) {
    const float* in = (const float*)d_in[0];
    float* out = (float*)d_out;
    (void)d_ws; (void)ws_size;
    // 24 planes x 16x16 tiles of 64x64
    fused_open<<<24 * 16 * 16, 256, 0, stream>>>(in, out);
}

// Round 3
// 187.647 us; speedup vs baseline: 1.4986x; 1.3360x over previous
//
#include <hip/hip_runtime.h>

// Fused morphological opening (22x22 flat SE), 8x3x1024x1024 f32, one kernel.
// opening = dilate(erode(x)); both separable. Per 64x64 output tile:
//   P0: colmin streamed global->regs->LDS (vertical van Herk in registers,
//       writes 85 rows x 108 cols of column-min into B; no input staging)
//   P1: rowmin over B rows -> eroded 85x85 (+ -inf border override), in-place
//   P2: rowmax over eroded rows -> 85x64, in-place
//   P3: colmax over B cols -> 64x64, direct coalesced global store
// B stride 112: every f4 access aligned; row-direction f4 ops conflict-free,
// col-direction scalar ops 2-way bank aliased (free on CDNA4).
// Window for index i: [i-11, i+10]. Erosion pads +inf outside image; eroded
// values outside the image are -inf for the dilation (border override in P1).

#define HH 1024
#define WW 1024
#define KW 22
#define SB 112
#define PINF __builtin_inff()

template<bool IS_MIN>
__device__ __forceinline__ float vop(float a, float b) {
    return IS_MIN ? fminf(a, b) : fmaxf(a, b);
}

// van Herk / Gil-Werman 1D sliding window (window KW=22), cout<=CMAX outputs.
// get(p): input at window-space p (output k's window = get(k..k+21)).
template<bool IS_MIN, int CMAX, class Get, class Put>
__device__ __forceinline__ void vanherk(int cout, Get get, Put put) {
    const float ID = IS_MIN ? PINF : -PINF;
    constexpr int NB = (CMAX + 2 * KW - 2) / KW;
    float Sprev[KW];
    #pragma unroll
    for (int j = 0; j < NB; ++j) {
        const int base = KW * j;
        int needed = cout + KW - 1 - base;
        if (needed > KW) needed = KW;
        float v[KW];
        #pragma unroll
        for (int m = 0; m < KW; ++m)
            v[m] = (m < needed) ? get(base + m) : ID;
        float p = ID;
        #pragma unroll
        for (int m = 0; m < KW; ++m) {
            p = vop<IS_MIN>(p, v[m]);
            const int k = base - (KW - 1) + m;
            if (k >= 0) {
                if (m == KW - 1) {
                    if (k < cout) put(k, p);
                } else {
                    if (k < cout) put(k, vop<IS_MIN>(Sprev[m + 1], p));
                }
            }
        }
        if (j < NB - 1) {
            float s = ID;
            #pragma unroll
            for (int m = KW - 1; m >= 0; --m) {
                s = vop<IS_MIN>(s, v[m]);
                Sprev[m] = s;
            }
        }
    }
}

template<bool INTERIOR>
__device__ __forceinline__ void tile_body(const float* __restrict__ src,
                                          float* __restrict__ dst,
                                          int R, int C, float* B, int t) {
    // ---- P0: colmin, global -> B[85][SB] cols j in [0,108) ----
    // B row o = img row R-11+o; window = img rows [R-22+o, R-1+o].
    if (t < 216) {
        const int ch = t >= 108;
        const int j = t - ch * 108;
        const int base_o = ch ? 43 : 0;
        const int cout = ch ? 42 : 43;
        int cj = C - 22 + j;
        bool colOK = true;
        if (!INTERIOR) {
            colOK = (unsigned)cj < WW;
            cj = cj < 0 ? 0 : (cj > WW - 1 ? WW - 1 : cj);
        }
        const float* col = src + cj;
        const int rbase = R - 22 + base_o;
        vanherk<true, 43>(cout,
            [&](int p) {
                int r = rbase + p;
                if (INTERIOR) return col[r * WW];
                int rc = r < 0 ? 0 : (r > HH - 1 ? HH - 1 : r);
                float v = col[rc * WW];
                return (colOK && (unsigned)r < HH) ? v : PINF;
            },
            [&](int k, float v) { B[(base_o + k) * SB + j] = v; });
    }
    __syncthreads();

    // ---- P1: rowmin -> eroded(o, e), e in [0,85), in-place ----
    // eroded e = img col C-11+e; window = B cols [e, e+21].
    {
        float res[44];
        const bool act = t < 170;
        int o = 0, e0 = 0;
        if (act) {
            o = t >> 1;
            const int ch = t & 1;
            e0 = ch ? 44 : 0;
            const int cout = ch ? 41 : 44;
            const int n = cout + KW - 1;              // 65 / 62 inputs
            float in[68];
            const float4* Br = (const float4*)(B + o * SB + e0);
            #pragma unroll
            for (int i = 0; i < 17; ++i) {
                if (4 * i < n) {
                    float4 x = Br[i];
                    in[4 * i] = x.x; in[4 * i + 1] = x.y;
                    in[4 * i + 2] = x.z; in[4 * i + 3] = x.w;
                }
            }
            vanherk<true, 44>(cout,
                [&](int p) { return in[p]; },
                [&](int k, float v) { res[k] = v; });
            if (!INTERIOR) {
                const bool rOK = (unsigned)(R - 11 + o) < HH;
                #pragma unroll
                for (int k = 0; k < 44; ++k) {
                    const int cimg = C - 11 + e0 + k;
                    if (!rOK || (unsigned)cimg >= WW) res[k] = -PINF;
                }
            }
        }
        __syncthreads();
        if (act) {
            float4* Bw = (float4*)(B + o * SB + e0);
            #pragma unroll
            for (int i = 0; i < 11; ++i)   // cols >=85 get garbage; never read
                Bw[i] = make_float4(res[4 * i], res[4 * i + 1],
                                    res[4 * i + 2], res[4 * i + 3]);
        }
        __syncthreads();
    }

    // ---- P2: rowmax(o, c), c in [0,64): window = eroded cols [c, c+21] ----
    {
        float res[32];
        const bool act = t < 170;
        int o = 0, c0 = 0;
        if (act) {
            o = t >> 1;
            c0 = (t & 1) * 32;
            float in[56];                              // cols [c0, c0+52] used
            const float4* Br = (const float4*)(B + o * SB + c0);
            #pragma unroll
            for (int i = 0; i < 14; ++i) {
                float4 x = Br[i];
                in[4 * i] = x.x; in[4 * i + 1] = x.y;
                in[4 * i + 2] = x.z; in[4 * i + 3] = x.w;
            }
            vanherk<false, 32>(32,
                [&](int p) { return in[p]; },
                [&](int k, float v) { res[k] = v; });
        }
        __syncthreads();
        if (act) {
            float4* Bw = (float4*)(B + o * SB + c0);
            #pragma unroll
            for (int i = 0; i < 8; ++i)
                Bw[i] = make_float4(res[4 * i], res[4 * i + 1],
                                    res[4 * i + 2], res[4 * i + 3]);
        }
        __syncthreads();
    }

    // ---- P3: colmax -> out. out row R+y: window = B rows [y, y+21] ----
    {
        const int c = t & 63;
        const int y0 = (t >> 6) << 4;                  // {0,16,32,48}
        float o16[16];
        vanherk<false, 16>(16,
            [&](int p) { return B[(y0 + p) * SB + c]; },
            [&](int k, float v) { o16[k] = v; });
        #pragma unroll
        for (int k = 0; k < 16; ++k)
            dst[(R + y0 + k) * WW + C + c] = o16[k];
    }
}

__global__ __launch_bounds__(256) void fused_open(const float* __restrict__ in,
                                                  float* __restrict__ out) {
    __shared__ float B[85 * SB];                       // 38,080 B
    const int t = threadIdx.x;
    const int b = blockIdx.x;
    const int plane = b >> 8;
    const int by = (b >> 4) & 15;
    const int bx = b & 15;
    const int R = by * 64, C = bx * 64;
    const float* src = in + (size_t)plane * (HH * WW);
    float* dst = out + (size_t)plane * (HH * WW);

    if (by >= 1 && by <= 14 && bx >= 1 && bx <= 14)
        tile_body<true>(src, dst, R, C, B, t);
    else
        tile_body<false>(src, dst, R, C, B, t);
}

extern "C" void kernel_launch(void* const* d_in, const int* in_sizes, int n_in,
                              void* d_out, int out_size, void* d_ws, size_t ws_size,
                              hipStream_t stream) {
    const float* in = (const float*)d_in[0];
    float* out = (float*)d_out;
    (void)d_ws; (void)ws_size;
    fused_open<<<24 * 16 * 16, 256, 0, stream>>>(in, out);
}